// Round 1
// baseline (544.233 us; speedup 1.0000x reference)
//
#include <hip/hip_runtime.h>
#include <hip/hip_bf16.h>

typedef float f32x4 __attribute__((ext_vector_type(4)));
typedef short s16x8 __attribute__((ext_vector_type(8)));

#define NB   256
#define NU   512
#define ND0  512
#define ND1  1024
#define WROW (ND0 * ND1)   // elements per u-row of w

__device__ __forceinline__ unsigned int f2bf_pk(float a, float b) {
  __hip_bfloat16 ha = __float2bfloat16(a);
  __hip_bfloat16 hb = __float2bfloat16(b);
  unsigned short ua, ub;
  __builtin_memcpy(&ua, &ha, 2);
  __builtin_memcpy(&ub, &hb, 2);
  return (unsigned int)ua | ((unsigned int)ub << 16);
}

// CK-style barrier: enforces LDS ordering but does NOT drain vmcnt,
// so register-prefetch global loads stay in flight across it.
__device__ __forceinline__ void block_sync_lds() {
  asm volatile("s_waitcnt lgkmcnt(0)" ::: "memory");
  __builtin_amdgcn_s_barrier();
}

// Seed out[b,u] = bias[u]; main kernel atomically accumulates on top.
__global__ __launch_bounds__(256) void init_out(const float* __restrict__ bias,
                                                float* __restrict__ out) {
  int idx = blockIdx.x * 256 + threadIdx.x;   // 512 blocks -> 131072 = 256*512
  out[idx] = bias[idx & (NU - 1)];
}

// out(256x512) = Z(256x524288) @ W^T, Z[b, i*1024+j] = x[b,i]*y[b,j].
// Grid: 512 blocks = 4 u-tiles (BN=128) x 128 K-chunks.
// Block: 512 threads, 8 waves (2m x 4n); per-wave 8 m-frags x 2 n-frags.
//
// vmcnt discipline (vmcnt retires in FIFO issue order!):
//   per iteration, issue order is [y x8] -> pack(WCUR, counted vmcnt(8))
//   -> [WNXT x4] -> A-synth (counted vmcnt(8)/vmcnt(4): waits only y).
//   The W prefetch is always the YOUNGEST vmem in the FIFO, so no wait
//   ever drains it: W loads stay in flight across barrier2 + MFMA +
//   barrier1 and retire at the next iteration's pack. The 2x manual
//   unroll (wvA/wvB alternation) removes the old wv=wvn copy and its
//   vmcnt(0) full-drain.
__global__ __launch_bounds__(512, 4) void bilinear_kern(
    const float* __restrict__ x, const float* __restrict__ y,
    const float* __restrict__ w, float* __restrict__ out) {
  __shared__ char Alds[32768];   // 256 rows x 128B (64 bf16), XOR-swizzled
  __shared__ char Wlds[16384];   // 128 rows x 128B (64 bf16), XOR-swizzled

  const int t    = threadIdx.x;
  const int lane = t & 63;
  const int l15  = lane & 15;
  const int lk   = lane >> 4;          // 0..3
  const int wid  = t >> 6;             // 0..7
  const int wm   = wid >> 2;           // 0..1  (m-group: rows wm*128)
  const int wn   = wid & 3;            // 0..3  (n-group: cols wn*32)

  const int nt    = blockIdx.x & 3;    // u-tile
  const int ic    = blockIdx.x >> 2;   // K-chunk: i0 in [ic*4, ic*4+4)
  // Per-block K-phase stagger: decorrelates the DRAM bursts of the 4
  // u-tile blocks sharing one ic (different ii granule) and spreads j0
  // phases across ic's. Each block still covers its K-chunk exactly once.
  const int off   = (nt << 4) | (ic & 15);
  const int ucol0 = nt * 128 + wn * 32;

  f32x4 acc[8][2];
#pragma unroll
  for (int mf = 0; mf < 8; ++mf)
#pragma unroll
    for (int nf = 0; nf < 2; ++nf)
#pragma unroll
      for (int r = 0; r < 4; ++r) acc[mf][nf][r] = 0.0f;

  // --- A staging map: thread covers rows ar+32p (p=0..7), floats l15*4..+4 ---
  const int ar   = t >> 4;                        // 0..31
  const int aswz = (ar & 7) << 4;                 // (row&7) invariant under +32p
  const int awr  = ar * 128 + ((l15 * 8) ^ aswz); // +p*4096
  const float* yb = y + (size_t)ar * ND1 + l15 * 4;

  // --- W staging map: thread covers rows wrb+4q (q=0..3), floats l15*4..+4 ---
  const int wrb = wid * 16 + lk;                  // 0..127
  const float* wq = w + (size_t)(nt * 128 + wrb) * WROW + l15 * 4;

  // frag-read swizzle: frag rows are l15 mod 8 in both tiles
  const int afswz = (l15 & 7) << 4;

  // ---- prologue: prefetch step-0's W and its x column ----
  f32x4 wvA[4], wvB[4];
  float xv[8];
  {
    const int s0  = off;
    const int ii0 = ic * 4 + (s0 >> 4);
    const int j00 = (s0 & 15) * 64;
    const float* p0 = wq + (size_t)ii0 * ND1 + j00;
#pragma unroll
    for (int q = 0; q < 4; ++q)
      wvA[q] = *(const f32x4*)(p0 + (size_t)q * 4 * WROW);
#pragma unroll
    for (int p = 0; p < 8; ++p)
      xv[p] = x[(size_t)(ar + 32 * p) * ND0 + ii0];
  }

#define BODY(IT, WCUR, WNXT)                                                  \
  {                                                                           \
    const int s  = ((IT) + off) & 63;                                         \
    const int j0 = (s & 15) * 64;                                             \
    block_sync_lds(); /* barrier1: previous tiles fully consumed */           \
    /* (1) issue ALL y row-loads first (L2-resident, ~1MB) */                 \
    f32x4 v[8];                                                               \
    _Pragma("unroll")                                                         \
    for (int p = 0; p < 8; ++p)                                               \
      v[p] = *(const f32x4*)(yb + (size_t)p * 32 * ND1 + j0);                 \
    /* (2) pack WCUR (in flight for a full iteration) -> Wlds.         */    \
    /*     Counted wait (WCUR oldest in FIFO) ~ no stall; frees 16 regs */    \
    _Pragma("unroll")                                                         \
    for (int q = 0; q < 4; ++q) {                                             \
      const int row  = wrb + 4 * q;                                           \
      const int byte = row * 128 + ((l15 * 8) ^ ((row & 7) << 4));            \
      unsigned long long pk =                                                 \
          (unsigned long long)f2bf_pk(WCUR[q][0], WCUR[q][1]) |               \
          ((unsigned long long)f2bf_pk(WCUR[q][2], WCUR[q][3]) << 32);        \
      *(unsigned long long*)(Wlds + byte) = pk;                               \
    }                                                                         \
    /* (3) issue next step's W loads AFTER all y issues: every later   */     \
    /*     y-wait is a counted vmcnt that leaves these in flight       */     \
    if ((IT) < 63) {                                                          \
      const int sn  = (s + 1) & 63;                                           \
      const int iin = ic * 4 + (sn >> 4);                                     \
      const int jn  = (sn & 15) * 64;                                         \
      const float* pn = wq + (size_t)iin * ND1 + jn;                          \
      _Pragma("unroll")                                                       \
      for (int q = 0; q < 4; ++q)                                             \
        WNXT[q] = *(const f32x4*)(pn + (size_t)q * 4 * WROW);                 \
    }                                                                         \
    /* (4) A-tile synth: SY[b,jj] = bf16(x[b,i0]*y[b,j0+jj]) */               \
    _Pragma("unroll")                                                         \
    for (int p = 0; p < 8; ++p) {                                             \
      unsigned long long pk =                                                 \
          (unsigned long long)f2bf_pk(xv[p] * v[p][0], xv[p] * v[p][1]) |     \
          ((unsigned long long)f2bf_pk(xv[p] * v[p][2], xv[p] * v[p][3])      \
           << 32);                                                            \
      *(unsigned long long*)(Alds + awr + p * 4096) = pk;                     \
    }                                                                         \
    /* (5) x column rollover for NEXT step (must be after A-synth: xv   */    \
    /*     is consumed above in this same step)                          */   \
    if ((IT) < 63 && (s & 15) == 15) {                                        \
      const int iin = ic * 4 + (((s + 1) & 63) >> 4);                         \
      _Pragma("unroll")                                                       \
      for (int pp = 0; pp < 8; ++pp)                                          \
        xv[pp] = x[(size_t)(ar + 32 * pp) * ND0 + iin];                       \
    }                                                                         \
    block_sync_lds(); /* barrier2: tiles visible (lgkmcnt only) */            \
    /* (6) MFMA over BK=64 (two k-steps of 32) */                             \
    _Pragma("unroll")                                                         \
    for (int ks = 0; ks < 2; ++ks) {                                          \
      const int kcol = ks * 64;                                               \
      s16x8 bfr[2];                                                           \
      _Pragma("unroll")                                                       \
      for (int nf = 0; nf < 2; ++nf) {                                        \
        const int row = wn * 32 + nf * 16 + l15;                              \
        bfr[nf] = *(const s16x8*)(Wlds + row * 128 + ((kcol + lk * 16) ^ afswz)); \
      }                                                                       \
      _Pragma("unroll")                                                       \
      for (int mf = 0; mf < 8; ++mf) {                                        \
        const int row = wm * 128 + mf * 16 + l15;                             \
        s16x8 af = *(const s16x8*)(Alds + row * 128 + ((kcol + lk * 16) ^ afswz)); \
        acc[mf][0] = __builtin_amdgcn_mfma_f32_16x16x32_bf16(af, bfr[0], acc[mf][0], 0, 0, 0); \
        acc[mf][1] = __builtin_amdgcn_mfma_f32_16x16x32_bf16(af, bfr[1], acc[mf][1], 0, 0, 0); \
      }                                                                       \
    }                                                                         \
  }

  // 64 K-steps, manually 2x-unrolled so wvA/wvB alternate roles:
  // no register copy, no vmcnt(0) drain anywhere in the main loop.
  for (int ot = 0; ot < 32; ++ot) {
    BODY(2 * ot,     wvA, wvB)
    BODY(2 * ot + 1, wvB, wvA)
  }
#undef BODY

  // ---- epilogue: atomic accumulate partial tile into out ----
  // C/D layout: col = lane&15, row = (lane>>4)*4 + reg
#pragma unroll
  for (int mf = 0; mf < 8; ++mf) {
    const int grow = wm * 128 + mf * 16 + lk * 4;
#pragma unroll
    for (int nf = 0; nf < 2; ++nf) {
      const int gcol = ucol0 + nf * 16 + l15;
#pragma unroll
      for (int r = 0; r < 4; ++r) {
        atomicAdd(out + (size_t)(grow + r) * NU + gcol, acc[mf][nf][r]);
      }
    }
  }
}

extern "C" void kernel_launch(void* const* d_in, const int* in_sizes, int n_in,
                              void* d_out, int out_size, void* d_ws, size_t ws_size,
                              hipStream_t stream) {
  const float* x    = (const float*)d_in[0];
  const float* y    = (const float*)d_in[1];
  const float* w    = (const float*)d_in[2];
  const float* bias = (const float*)d_in[3];
  float* out = (float*)d_out;

  init_out<<<512, 256, 0, stream>>>(bias, out);
  bilinear_kern<<<512, 512, 0, stream>>>(x, y, w, out);
}